// Round 2
// baseline (4155.089 us; speedup 1.0000x reference)
//
#include <hip/hip_runtime.h>
#include <math.h>

// ws offsets (in floats)
#define OFF_Q   0u
#define OFF_K   524288u
#define OFF_V   1048576u
#define OFF_AX  1572864u
#define OFF_H0  2097152u
#define OFF_C   2621440u
#define OFF_H1  3145728u
#define OFF_WT  3670016u   // 294912 floats: [ic][ky][kx][oc]
#define OFF_ZC  3964928u   // 2097152 floats: conv pre-activations [b][256][1024]

// ---------------------------------------------------------------------------
// Transpose conv weights [oc][ic][ky][kx] -> [ (ic*3+ky)*3+kx ][oc]
__global__ __launch_bounds__(256) void k_wtrans(const float* __restrict__ conv_w,
                                                float* __restrict__ wT) {
    int idx = blockIdx.x * 256 + threadIdx.x;   // 294912 total
    if (idx >= 294912) return;
    int oc = idx & 255;
    int r  = idx >> 8;                          // ic*9 + ky*3 + kx
    wT[idx] = conv_w[oc * 1152 + r];
}

// ---------------------------------------------------------------------------
// QKV projection for timestep t. q/k/v stored as [b][o][n].
__global__ __launch_bounds__(256) void k_qkv(
    const float* __restrict__ X,
    const float* __restrict__ qw, const float* __restrict__ qb,
    const float* __restrict__ kw, const float* __restrict__ kb,
    const float* __restrict__ vw, const float* __restrict__ vb,
    float* __restrict__ qs, float* __restrict__ ks, float* __restrict__ vs,
    int t)
{
    __shared__ float xs[64][64];
    const int tid    = threadIdx.x;
    const int ntile  = blockIdx.x;   // 0..15 (64 n each)
    const int b      = blockIdx.y;   // 0..7
    const int osplit = blockIdx.z;   // 0..3 (48 outputs each)

    const float* xbase = X + ((size_t)(b * 64) * 16 + t) * 1024 + ntile * 64;
    for (int i = tid; i < 4096; i += 256) {
        int c = i >> 6, n = i & 63;
        xs[c][n] = xbase[(size_t)c * 16384 + n];
    }
    __syncthreads();

    const int og = __builtin_amdgcn_readfirstlane(tid >> 6);  // 0..3, wave-uniform
    const int n  = tid & 63;
    const int o0 = osplit * 48 + og * 12;

    float acc[12];
#pragma unroll
    for (int j = 0; j < 12; ++j) acc[j] = 0.f;

    for (int c0 = 0; c0 < 64; c0 += 16) {
        float xv[16];
#pragma unroll
        for (int cc = 0; cc < 16; ++cc) xv[cc] = xs[c0 + cc][n];
#pragma unroll
        for (int j = 0; j < 12; ++j) {
            int o = o0 + j;
            const float* wrow = (o < 64) ? (qw + o * 64)
                              : (o < 128) ? (kw + (o - 64) * 64)
                                          : (vw + (o - 128) * 64);
#pragma unroll
            for (int cc = 0; cc < 16; ++cc) acc[j] += wrow[c0 + cc] * xv[cc];
        }
    }

#pragma unroll
    for (int j = 0; j < 12; ++j) {
        int o = o0 + j;
        float* dst; float bias;
        if (o < 64)       { dst = qs + ((size_t)b * 64 + o)        * 1024; bias = qb[o]; }
        else if (o < 128) { dst = ks + ((size_t)b * 64 + (o - 64)) * 1024; bias = kb[o - 64]; }
        else              { dst = vs + ((size_t)b * 64 + (o - 128))* 1024; bias = vb[o - 128]; }
        dst[ntile * 64 + n] = acc[j] + bias;
    }
}

// ---------------------------------------------------------------------------
// Fused attention, 16 rows per block, m-tiles of 128.
// K read directly from global (L2-resident); V staged (transpose needed).
// thread: rg = tid>>5 (2 rows each), mlg = tid&31.
__global__ __launch_bounds__(256) void k_attn(
    const float* __restrict__ qs, const float* __restrict__ ks,
    const float* __restrict__ vs, float* __restrict__ ax)
{
    __shared__ float q_lds[16][65];
    __shared__ __align__(16) float v_lds[128][68];   // [m][c]
    __shared__ __align__(16) float p_lds[16][132];

    const int tid = threadIdx.x;
    const int n0  = blockIdx.x * 16;
    const int b   = blockIdx.y;
    const float* qb_ = qs + (size_t)b * 65536;
    const float* kb_ = ks + (size_t)b * 65536;
    const float* vb_ = vs + (size_t)b * 65536;

    for (int i = tid; i < 1024; i += 256) {
        int o = i >> 4, r = i & 15;
        q_lds[r][o] = qb_[o * 1024 + n0 + r];
    }

    const int rg  = tid >> 5;   // 0..7 -> rows n0 + rg*2 + rr
    const int mlg = tid & 31;
    const int ch  = mlg & 7;    // PV: c = 8*ch + cc
    const int mh  = mlg >> 3;   // PV: m = mh + 4*j
    const int r0  = rg * 2;

    float m_run[2], l_run[2], acc[2][8];
#pragma unroll
    for (int rr = 0; rr < 2; ++rr) {
        m_run[rr] = -1e30f; l_run[rr] = 0.f;
#pragma unroll
        for (int cc = 0; cc < 8; ++cc) acc[rr][cc] = 0.f;
    }

    for (int mt = 0; mt < 8; ++mt) {
        // stage V tile (128 m x 64 c, transposed)
        for (int i = tid; i < 8192; i += 256) {
            int c = i >> 7, m = i & 127;
            v_lds[m][c] = vb_[c * 1024 + mt * 128 + m];
        }
        __syncthreads();

        // QK^T: thread computes m = mlg*4 + jj (f4 K loads from global)
        float s[2][4];
#pragma unroll
        for (int rr = 0; rr < 2; ++rr)
#pragma unroll
            for (int jj = 0; jj < 4; ++jj) s[rr][jj] = 0.f;
        for (int o = 0; o < 64; ++o) {
            float q0 = q_lds[r0][o];
            float q1 = q_lds[r0 + 1][o];
            float4 kv = *reinterpret_cast<const float4*>(
                kb_ + o * 1024 + mt * 128 + mlg * 4);
            float kk[4] = {kv.x, kv.y, kv.z, kv.w};
#pragma unroll
            for (int jj = 0; jj < 4; ++jj) {
                s[0][jj] += q0 * kk[jj];
                s[1][jj] += q1 * kk[jj];
            }
        }

        // online softmax (reduce over the 32 mlg lanes of this row group)
        float p[2][4];
#pragma unroll
        for (int rr = 0; rr < 2; ++rr) {
            float tmax = s[rr][0];
#pragma unroll
            for (int jj = 1; jj < 4; ++jj) tmax = fmaxf(tmax, s[rr][jj]);
#pragma unroll
            for (int d = 1; d < 32; d <<= 1) tmax = fmaxf(tmax, __shfl_xor(tmax, d, 64));
            float nm = fmaxf(m_run[rr], tmax);
            float sc = expf(m_run[rr] - nm);
            float tsum = 0.f;
#pragma unroll
            for (int jj = 0; jj < 4; ++jj) { p[rr][jj] = expf(s[rr][jj] - nm); tsum += p[rr][jj]; }
#pragma unroll
            for (int d = 1; d < 32; d <<= 1) tsum += __shfl_xor(tsum, d, 64);
            l_run[rr] = l_run[rr] * sc + tsum;
            m_run[rr] = nm;
#pragma unroll
            for (int cc = 0; cc < 8; ++cc) acc[rr][cc] *= sc;
        }

        // publish p (f4 store, m = mlg*4 + jj)
#pragma unroll
        for (int rr = 0; rr < 2; ++rr)
            *reinterpret_cast<float4*>(&p_lds[r0 + rr][mlg * 4]) =
                make_float4(p[rr][0], p[rr][1], p[rr][2], p[rr][3]);
        __syncthreads();

        // PV: thread covers c = 8*ch..+7, m = mh + 4*j
#pragma unroll 4
        for (int j = 0; j < 32; ++j) {
            int m = mh + 4 * j;
            float pv0 = p_lds[r0][m];
            float pv1 = p_lds[r0 + 1][m];
            const float4* vp = reinterpret_cast<const float4*>(&v_lds[m][ch * 8]);
            float4 v0 = vp[0], v1 = vp[1];
            float vv[8] = {v0.x, v0.y, v0.z, v0.w, v1.x, v1.y, v1.z, v1.w};
#pragma unroll
            for (int cc = 0; cc < 8; ++cc) {
                acc[0][cc] += pv0 * vv[cc];
                acc[1][cc] += pv1 * vv[cc];
            }
        }
        __syncthreads();   // PV done before next tile restages v/p
    }

    // combine the 4 m-quarter partials (mh = tid bits 3,4)
#pragma unroll
    for (int rr = 0; rr < 2; ++rr)
#pragma unroll
        for (int cc = 0; cc < 8; ++cc) {
            float a = acc[rr][cc];
            a += __shfl_xor(a, 8, 64);
            a += __shfl_xor(a, 16, 64);
            acc[rr][cc] = a;
        }
    if (mh == 0) {
        float* axb = ax + (size_t)b * 65536;
#pragma unroll
        for (int rr = 0; rr < 2; ++rr) {
            float inv = 1.f / l_run[rr];
#pragma unroll
            for (int cc = 0; cc < 8; ++cc)
                axb[(ch * 8 + cc) * 1024 + n0 + r0 + rr] = acc[rr][cc] * inv;
        }
    }
}

// ---------------------------------------------------------------------------
// 3x3 conv (128->256) pre-activations, oc split in quarters across blocks.
// block: (tile 8w x 4h, b, ocq). Writes zc[b][256][1024].
__global__ __launch_bounds__(256) void k_conv2(
    const float* __restrict__ ax, const float* __restrict__ hin,
    float* __restrict__ zc, const float* __restrict__ wT,
    const float* __restrict__ conv_b)
{
    __shared__ float z_lds[128][60];     // [ic][row*10+col], 6 rows, 10 cols (halo)

    const int tid  = threadIdx.x;
    const int tile = blockIdx.x;         // 0..31
    const int b    = blockIdx.y;
    const int q    = blockIdx.z;         // 0..3 -> oc quarter
    const int x0   = (tile & 3) * 8;
    const int y0   = (tile >> 2) * 4;
    const float* axb = ax  + (size_t)b * 65536;
    const float* hb  = hin + (size_t)b * 65536;

    for (int i = tid; i < 7680; i += 256) {
        int ic  = i / 60;
        int rem = i - ic * 60;
        int row = rem / 10;
        int col = rem - row * 10;
        int gy = y0 + row - 1, gx = x0 + col - 1;
        float v = 0.f;
        if ((unsigned)gy < 32u && (unsigned)gx < 32u) {
            const float* src = (ic < 64) ? (axb + ic * 1024) : (hb + (ic - 64) * 1024);
            v = src[gy * 32 + gx];
        }
        z_lds[ic][rem] = v;
    }
    __syncthreads();

    const int ocg4 = tid >> 4;           // 0..15 -> 4 oc each
    const int pxp  = tid & 15;           // y = pxp>>2, x = (pxp&3)*2 (2 px each)
    const int y    = pxp >> 2;
    const int x    = (pxp & 3) * 2;
    const int oc0  = q * 64 + ocg4 * 4;

    float acc[2][4];
#pragma unroll
    for (int oo = 0; oo < 4; ++oo) {
        float bv = conv_b[oc0 + oo];
        acc[0][oo] = bv; acc[1][oo] = bv;
    }

    for (int ic = 0; ic < 128; ++ic) {
#pragma unroll
        for (int ky = 0; ky < 3; ++ky) {
            const float2* zp = reinterpret_cast<const float2*>(
                &z_lds[ic][(y + ky) * 10 + x]);
            float2 za = zp[0], zb = zp[1];
            float in4[4] = {za.x, za.y, zb.x, zb.y};
#pragma unroll
            for (int kx = 0; kx < 3; ++kx) {
                float4 w = *reinterpret_cast<const float4*>(
                    wT + ((ic * 3 + ky) * 3 + kx) * 256 + oc0);
                float wv[4] = {w.x, w.y, w.z, w.w};
#pragma unroll
                for (int oo = 0; oo < 4; ++oo) {
                    acc[0][oo] += wv[oo] * in4[kx];
                    acc[1][oo] += wv[oo] * in4[kx + 1];
                }
            }
        }
    }

    const int n = (y0 + y) * 32 + x0 + x;
#pragma unroll
    for (int oo = 0; oo < 4; ++oo) {
        *reinterpret_cast<float2*>(zc + ((size_t)b * 256 + oc0 + oo) * 1024 + n) =
            make_float2(acc[0][oo], acc[1][oo]);
    }
}

// ---------------------------------------------------------------------------
// Gate math: fully coalesced float4 streams.
__global__ __launch_bounds__(256) void k_gates(
    const float* __restrict__ zc, float* __restrict__ cst,
    float* __restrict__ hout, const float* __restrict__ wci,
    const float* __restrict__ wcf, const float* __restrict__ wco,
    float* __restrict__ out, int t)
{
    int idx = blockIdx.x * 256 + threadIdx.x;   // 131072 threads, 4 floats each
    int n4  = idx & 255;
    int chb = idx >> 8;
    int ch  = chb & 63;
    int b   = chb >> 6;

    size_t gbase = ((size_t)b * 256 + ch) * 1024 + n4 * 4;
    float4 ic4 = *reinterpret_cast<const float4*>(zc + gbase);
    float4 fc4 = *reinterpret_cast<const float4*>(zc + gbase + 65536);
    float4 gc4 = *reinterpret_cast<const float4*>(zc + gbase + 131072);
    float4 oc4 = *reinterpret_cast<const float4*>(zc + gbase + 196608);

    size_t sbase = ((size_t)b * 64 + ch) * 1024 + n4 * 4;
    float4 c4 = *reinterpret_cast<const float4*>(cst + sbase);
    size_t pbase = (size_t)ch * 1024 + n4 * 4;
    float4 wi4 = *reinterpret_cast<const float4*>(wci + pbase);
    float4 wf4 = *reinterpret_cast<const float4*>(wcf + pbase);
    float4 wo4 = *reinterpret_cast<const float4*>(wco + pbase);

    float icv[4] = {ic4.x, ic4.y, ic4.z, ic4.w};
    float fcv[4] = {fc4.x, fc4.y, fc4.z, fc4.w};
    float gcv[4] = {gc4.x, gc4.y, gc4.z, gc4.w};
    float ocv[4] = {oc4.x, oc4.y, oc4.z, oc4.w};
    float cv[4]  = {c4.x, c4.y, c4.z, c4.w};
    float wiv[4] = {wi4.x, wi4.y, wi4.z, wi4.w};
    float wfv[4] = {wf4.x, wf4.y, wf4.z, wf4.w};
    float wov[4] = {wo4.x, wo4.y, wo4.z, wo4.w};
    float nc[4], nh[4];
#pragma unroll
    for (int k = 0; k < 4; ++k) {
        float iv = 1.f / (1.f + expf(-(icv[k] + wiv[k] * cv[k])));
        float fv = 1.f / (1.f + expf(-(fcv[k] + wfv[k] * cv[k])));
        nc[k] = fv * cv[k] + iv * tanhf(gcv[k]);
        float ov = 1.f / (1.f + expf(-(ocv[k] + wov[k] * nc[k])));
        nh[k] = ov * tanhf(nc[k]);
    }

    *reinterpret_cast<float4*>(cst + sbase)  = make_float4(nc[0], nc[1], nc[2], nc[3]);
    *reinterpret_cast<float4*>(hout + sbase) = make_float4(nh[0], nh[1], nh[2], nh[3]);
    size_t obase = (((size_t)b * 64 + ch) * 16 + t) * 1024 + n4 * 4;
    *reinterpret_cast<float4*>(out + obase)  = make_float4(nh[0], nh[1], nh[2], nh[3]);
}

// ---------------------------------------------------------------------------
extern "C" void kernel_launch(void* const* d_in, const int* in_sizes, int n_in,
                              void* d_out, int out_size, void* d_ws, size_t ws_size,
                              hipStream_t stream)
{
    const float* X   = (const float*)d_in[0];
    const float* qw  = (const float*)d_in[1];
    const float* qb  = (const float*)d_in[2];
    const float* kw  = (const float*)d_in[3];
    const float* kb  = (const float*)d_in[4];
    const float* vw  = (const float*)d_in[5];
    const float* vb  = (const float*)d_in[6];
    const float* cw  = (const float*)d_in[7];
    const float* cb  = (const float*)d_in[8];
    const float* wci = (const float*)d_in[9];
    const float* wcf = (const float*)d_in[10];
    const float* wco = (const float*)d_in[11];
    float* out = (float*)d_out;
    float* ws  = (float*)d_ws;

    float* qs_ = ws + OFF_Q;
    float* ks_ = ws + OFF_K;
    float* vs_ = ws + OFF_V;
    float* ax_ = ws + OFF_AX;
    float* h0_ = ws + OFF_H0;
    float* c_  = ws + OFF_C;
    float* h1_ = ws + OFF_H1;
    float* wT_ = ws + OFF_WT;
    float* zc_ = ws + OFF_ZC;

    // zero h0 and c (adjacent regions)
    hipMemsetAsync(h0_, 0, 2u * 524288u * sizeof(float), stream);
    k_wtrans<<<1152, 256, 0, stream>>>(cw, wT_);

    for (int t = 0; t < 16; ++t) {
        k_qkv<<<dim3(16, 8, 4), 256, 0, stream>>>(X, qw, qb, kw, kb, vw, vb,
                                                  qs_, ks_, vs_, t);
        k_attn<<<dim3(64, 8), 256, 0, stream>>>(qs_, ks_, vs_, ax_);
        float* hin  = (t & 1) ? h1_ : h0_;
        float* hout = (t & 1) ? h0_ : h1_;
        k_conv2<<<dim3(32, 8, 4), 256, 0, stream>>>(ax_, hin, zc_, wT_, cb);
        k_gates<<<512, 256, 0, stream>>>(zc_, c_, hout, wci, wcf, wco, out, t);
    }
}

// Round 3
// 1577.480 us; speedup vs baseline: 2.6340x; 2.6340x over previous
//
#include <hip/hip_runtime.h>
#include <math.h>

typedef __attribute__((ext_vector_type(8))) __bf16 bf16x8;
typedef __attribute__((ext_vector_type(4))) float f32x4;
typedef unsigned short u16;
typedef unsigned int u32;

#define MFMA16(a, b, c) __builtin_amdgcn_mfma_f32_16x16x32_bf16(a, b, c, 0, 0, 0)

__device__ __forceinline__ u16 f2bf(float f) {
    u32 u = __float_as_uint(f);
    return (u16)((u + 0x7fffu + ((u >> 16) & 1u)) >> 16);   // RNE
}
__device__ __forceinline__ float bf2f(u16 h) {
    return __uint_as_float(((u32)h) << 16);
}

// ---------------------------------------------------------------------------
// conv weights fp32 [oc][ic][ky][kx] -> bf16 hi/lo [s=ky*3+kx][oc][ic] (ic contig)
__global__ __launch_bounds__(256) void k_wtrans2(const float* __restrict__ cw,
                                                 u16* __restrict__ whi,
                                                 u16* __restrict__ wlo) {
    int idx = blockIdx.x * 256 + threadIdx.x;
    if (idx >= 294912) return;
    int s = idx >> 15;
    int oc = (idx >> 7) & 255;
    int ic = idx & 127;
    float f = cw[oc * 1152 + ic * 9 + s];
    u16 hi = f2bf(f);
    whi[idx] = hi;
    wlo[idx] = f2bf(f - bf2f(hi));
}

// ---------------------------------------------------------------------------
// QKV for ALL (b,t).  qmat/kmat: [bt][n][d] bf16 (d contig). vt: [bt][c][m] bf16.
__global__ __launch_bounds__(256) void k_qkv(
    const float* __restrict__ X,
    const float* __restrict__ qw, const float* __restrict__ qb,
    const float* __restrict__ kw, const float* __restrict__ kb,
    const float* __restrict__ vw, const float* __restrict__ vb,
    u16* __restrict__ qmat, u16* __restrict__ kmat, u16* __restrict__ vt)
{
    __shared__ float sbuf[4096];
    const int tid    = threadIdx.x;
    const int ntile  = blockIdx.x;   // 0..15
    const int bt     = blockIdx.y;   // b*16 + t
    const int osplit = blockIdx.z;   // 0..3
    const int b = bt >> 4, t = bt & 15;

    const float* xbase = X + (size_t)b * 1048576 + (size_t)t * 1024 + ntile * 64;
    for (int i = tid; i < 4096; i += 256) {
        int c = i >> 6, n = i & 63;
        sbuf[c * 64 + n] = xbase[(size_t)c * 16384 + n];
    }
    __syncthreads();

    const int og = __builtin_amdgcn_readfirstlane(tid >> 6);
    const int n  = tid & 63;
    const int o0 = osplit * 48 + og * 12;

    float acc[12];
#pragma unroll
    for (int j = 0; j < 12; ++j) acc[j] = 0.f;

    for (int c0 = 0; c0 < 64; c0 += 16) {
        float xv[16];
#pragma unroll
        for (int cc = 0; cc < 16; ++cc) xv[cc] = sbuf[(c0 + cc) * 64 + n];
#pragma unroll
        for (int j = 0; j < 12; ++j) {
            int o = o0 + j;
            const float* wrow = (o < 64) ? (qw + o * 64)
                              : (o < 128) ? (kw + (o - 64) * 64)
                                          : (vw + (o - 128) * 64);
#pragma unroll
            for (int cc = 0; cc < 16; ++cc) acc[j] += wrow[c0 + cc] * xv[cc];
        }
    }

    // direct V writes (coalesced [c][m] bf16)
#pragma unroll
    for (int j = 0; j < 12; ++j) {
        int o = o0 + j;
        if (o >= 128)
            vt[(size_t)bt * 65536 + (o - 128) * 1024 + ntile * 64 + n] =
                f2bf(acc[j] + vb[o - 128]);
    }
    __syncthreads();   // all x reads done; sbuf can be reused
    // stash q/k (with bias) for transpose
#pragma unroll
    for (int j = 0; j < 12; ++j) {
        int o = o0 + j;
        if (o < 128) {
            float bias = (o < 64) ? qb[o] : kb[o - 64];
            sbuf[(og * 12 + j) * 65 + n] = acc[j] + bias;
        }
    }
    __syncthreads();

    if (osplit < 3) {
        const int tn = tid >> 2, oq = tid & 3;
#pragma unroll
        for (int k = 0; k < 6; ++k) {
            int o_l = oq * 12 + k * 2;
            int o_g = osplit * 48 + o_l;
            if (o_g < 128) {
                u32 pk = (u32)f2bf(sbuf[o_l * 65 + tn]) |
                         ((u32)f2bf(sbuf[(o_l + 1) * 65 + tn]) << 16);
                u16* base = (o_g < 64)
                    ? (qmat + (size_t)bt * 65536 + (ntile * 64 + tn) * 64 + o_g)
                    : (kmat + (size_t)bt * 65536 + (ntile * 64 + tn) * 64 + (o_g - 64));
                *reinterpret_cast<u32*>(base) = pk;
            }
        }
    }
}

// ---------------------------------------------------------------------------
// MFMA attention, all (b,t). ax output packed (hi | lo<<16) u32 at [bt][n][c].
// Swapped QK: C = K_tile(16m x 32d) @ Q(32d x 16n) -> lane owns P[m-sub][n=l15].
__global__ __launch_bounds__(256) void k_attn(
    const u16* __restrict__ qmat, const u16* __restrict__ kmat,
    const u16* __restrict__ vt, u32* __restrict__ ax)
{
    __shared__ u16 plds[4 * 16 * 40];    // per-wave [16 n][40 m-stride]
    const int tid = threadIdx.x;
    const int wv = tid >> 6, lane = tid & 63;
    const int l15 = lane & 15, l4 = lane >> 4;
    const int bt = blockIdx.y;
    const int n0 = blockIdx.x * 64 + wv * 16;

    const u16* qb_ = qmat + (size_t)bt * 65536;
    const u16* kb_ = kmat + (size_t)bt * 65536;
    const u16* vb_ = vt + (size_t)bt * 65536;

    bf16x8 qf0 = *reinterpret_cast<const bf16x8*>(qb_ + (n0 + l15) * 64 + l4 * 8);
    bf16x8 qf1 = *reinterpret_cast<const bf16x8*>(qb_ + (n0 + l15) * 64 + 32 + l4 * 8);

    f32x4 oacc[4];
#pragma unroll
    for (int ct = 0; ct < 4; ++ct) oacc[ct] = (f32x4){0.f, 0.f, 0.f, 0.f};
    float lsum = 0.f;

    char* plc = (char*)plds + wv * 1280;

    for (int mi = 0; mi < 32; ++mi) {
#pragma unroll
        for (int hf = 0; hf < 2; ++hf) {
            int mt = mi * 2 + hf;
            f32x4 s = {0.f, 0.f, 0.f, 0.f};
            const u16* ka = kb_ + (mt * 16 + l15) * 64 + l4 * 8;
            s = MFMA16(*reinterpret_cast<const bf16x8*>(ka), qf0, s);
            s = MFMA16(*reinterpret_cast<const bf16x8*>(ka + 32), qf1, s);
            float p0 = __expf(s[0]);
            float p1 = __expf(s[1]);
            float p2 = __expf(s[2]);
            float p3 = __expf(s[3]);
            lsum += (p0 + p1) + (p2 + p3);
            u32 pa = (u32)f2bf(p0) | ((u32)f2bf(p1) << 16);
            u32 pb = (u32)f2bf(p2) | ((u32)f2bf(p3) << 16);
            *reinterpret_cast<uint2*>(plc + l15 * 80 + hf * 32 + l4 * 8) =
                make_uint2(pa, pb);
        }
        bf16x8 pfrag = *reinterpret_cast<const bf16x8*>(plc + l15 * 80 + l4 * 16);
        const u16* vbase = vb_ + l15 * 1024 + mi * 32 + l4 * 8;
#pragma unroll
        for (int ct = 0; ct < 4; ++ct)
            oacc[ct] = MFMA16(pfrag,
                              *reinterpret_cast<const bf16x8*>(vbase + ct * 16384),
                              oacc[ct]);
    }

    lsum += __shfl_xor(lsum, 16, 64);
    lsum += __shfl_xor(lsum, 32, 64);

    u32* axb = ax + (size_t)bt * 65536;
#pragma unroll
    for (int r = 0; r < 4; ++r) {
        float linv = 1.f / __shfl(lsum, l4 * 4 + r, 64);
        int nrow = n0 + l4 * 4 + r;
#pragma unroll
        for (int ct = 0; ct < 4; ++ct) {
            float v = oacc[ct][r] * linv;
            u16 hi = f2bf(v);
            u16 lo = f2bf(v - bf2f(hi));
            axb[nrow * 64 + ct * 16 + l15] = (u32)hi | ((u32)lo << 16);
        }
    }
}

// ---------------------------------------------------------------------------
// Fused split-bf16 MFMA conv (3x3, 128->256) + ConvLSTM gates for one t.
// Block: 4 rows of the image (128 px) x 64 oc (one gate-quad group q).
// z LDS tile: [204 px][stride 80B] bf16 hi/lo, ic-chunked (4 chunks of 32).
__global__ __launch_bounds__(256) void k_cell(
    const u32* __restrict__ ax, const float* __restrict__ h_in,
    float* __restrict__ h_out, float* __restrict__ cst,
    const u16* __restrict__ whi, const u16* __restrict__ wlo,
    const float* __restrict__ conv_b,
    const float* __restrict__ wci, const float* __restrict__ wcf,
    const float* __restrict__ wco, float* __restrict__ out, int t)
{
    __shared__ u16 z_hi[204 * 40];
    __shared__ u16 z_lo[204 * 40];

    const int tid = threadIdx.x;
    const int sb = blockIdx.x;      // 0..7 -> rows y0..y0+3
    const int q  = blockIdx.y;      // 0..3 -> ch quarter
    const int b  = blockIdx.z;
    const int y0 = sb * 4;
    const int wv = tid >> 6, lane = tid & 63;
    const int l15 = lane & 15, l4 = lane >> 4;
    const int bt = b * 16 + t;

    f32x4 acc[4][2];
#pragma unroll
    for (int g = 0; g < 4; ++g)
#pragma unroll
        for (int ntw = 0; ntw < 2; ++ntw) acc[g][ntw] = (f32x4){0.f, 0.f, 0.f, 0.f};

    const u32* axb = ax + (size_t)bt * 65536;
    const float* hb = h_in + (size_t)b * 65536;

    for (int ck = 0; ck < 4; ++ck) {
        __syncthreads();   // previous iteration's LDS reads done
        if (ck < 2) {
            const int c0 = ck * 32;
            for (int i = tid; i < 6528; i += 256) {
                int p = i >> 5, c = i & 31;
                int row = p / 34, col = p - row * 34;
                int gy = y0 + row - 1, gx = col - 1;
                u32 v = 0;
                if ((unsigned)gy < 32u && (unsigned)gx < 32u)
                    v = axb[(gy * 32 + gx) * 64 + c0 + c];
                char* dst = (char*)z_hi + p * 80 + c * 2;
                *(u16*)dst = (u16)(v & 0xffffu);
                *(u16*)((char*)z_lo + p * 80 + c * 2) = (u16)(v >> 16);
            }
        } else {
            const int c0 = (ck - 2) * 32;
            for (int i = tid; i < 6528; i += 256) {
                int c = i / 204, p = i - c * 204;
                int row = p / 34, col = p - row * 34;
                int gy = y0 + row - 1, gx = col - 1;
                float f = 0.f;
                if ((unsigned)gy < 32u && (unsigned)gx < 32u)
                    f = hb[(c0 + c) * 1024 + gy * 32 + gx];
                u16 hi = f2bf(f);
                u16 lo = f2bf(f - bf2f(hi));
                *(u16*)((char*)z_hi + p * 80 + c * 2) = hi;
                *(u16*)((char*)z_lo + p * 80 + c * 2) = lo;
            }
        }
        __syncthreads();

        for (int s = 0; s < 9; ++s) {
            const int dy = s / 3 - 1, dx = s % 3 - 1;
            bf16x8 Ah[4], Al[4];
#pragma unroll
            for (int g = 0; g < 4; ++g) {
                int off = (s * 256 + g * 64 + q * 16 + l15) * 128 + ck * 32 + l4 * 8;
                Ah[g] = *reinterpret_cast<const bf16x8*>(whi + off);
                Al[g] = *reinterpret_cast<const bf16x8*>(wlo + off);
            }
#pragma unroll
            for (int ntw = 0; ntw < 2; ++ntw) {
                int px = (wv * 2 + ntw) * 16 + l15;
                int p = ((px >> 5) + 1 + dy) * 34 + (px & 31) + 1 + dx;
                bf16x8 Bh = *reinterpret_cast<const bf16x8*>((char*)z_hi + p * 80 + l4 * 16);
                bf16x8 Bl = *reinterpret_cast<const bf16x8*>((char*)z_lo + p * 80 + l4 * 16);
#pragma unroll
                for (int g = 0; g < 4; ++g) {
                    acc[g][ntw] = MFMA16(Ah[g], Bh, acc[g][ntw]);
                    acc[g][ntw] = MFMA16(Ah[g], Bl, acc[g][ntw]);
                    acc[g][ntw] = MFMA16(Al[g], Bh, acc[g][ntw]);
                }
            }
        }
    }

    // gates (all lane-local: g = i,f,g~,o for ch = q*16 + l4*4 + r, px = col l15)
#pragma unroll
    for (int ntw = 0; ntw < 2; ++ntw) {
#pragma unroll
        for (int r = 0; r < 4; ++r) {
            int px = (wv * 2 + ntw) * 16 + l15;
            int n = (y0 + (px >> 5)) * 32 + (px & 31);
            int ch = q * 16 + l4 * 4 + r;
            float ci = acc[0][ntw][r] + conv_b[ch];
            float cf = acc[1][ntw][r] + conv_b[64 + ch];
            float cg = acc[2][ntw][r] + conv_b[128 + ch];
            float co = acc[3][ntw][r] + conv_b[192 + ch];
            size_t si = ((size_t)b * 64 + ch) * 1024 + n;
            int pw = ch * 1024 + n;
            float cp = cst[si];
            float iv = 1.f / (1.f + expf(-(ci + wci[pw] * cp)));
            float fv = 1.f / (1.f + expf(-(cf + wcf[pw] * cp)));
            float nc = fv * cp + iv * tanhf(cg);
            float ov = 1.f / (1.f + expf(-(co + wco[pw] * nc)));
            float nh = ov * tanhf(nc);
            cst[si] = nc;
            h_out[(size_t)b * 65536 + ch * 1024 + n] = nh;
            out[(((size_t)b * 64 + ch) * 16 + t) * 1024 + n] = nh;
        }
    }
}

// ---------------------------------------------------------------------------
// ws layout (bytes); total ~91.4 MB
#define OB_Q   0ull
#define OB_K   16777216ull
#define OB_V   33554432ull
#define OB_AX  50331648ull
#define OB_WHI 83886080ull
#define OB_WLO 84475904ull
#define OB_H0  85065728ull
#define OB_C   87162880ull
#define OB_H1  89260032ull

extern "C" void kernel_launch(void* const* d_in, const int* in_sizes, int n_in,
                              void* d_out, int out_size, void* d_ws, size_t ws_size,
                              hipStream_t stream)
{
    const float* X   = (const float*)d_in[0];
    const float* qw  = (const float*)d_in[1];
    const float* qb  = (const float*)d_in[2];
    const float* kw  = (const float*)d_in[3];
    const float* kb  = (const float*)d_in[4];
    const float* vw  = (const float*)d_in[5];
    const float* vb  = (const float*)d_in[6];
    const float* cw  = (const float*)d_in[7];
    const float* cb  = (const float*)d_in[8];
    const float* wci = (const float*)d_in[9];
    const float* wcf = (const float*)d_in[10];
    const float* wco = (const float*)d_in[11];
    float* out = (float*)d_out;
    char* wsb  = (char*)d_ws;

    u16* qmat = (u16*)(wsb + OB_Q);
    u16* kmat = (u16*)(wsb + OB_K);
    u16* vt   = (u16*)(wsb + OB_V);
    u32* axp  = (u32*)(wsb + OB_AX);
    u16* whi  = (u16*)(wsb + OB_WHI);
    u16* wlo  = (u16*)(wsb + OB_WLO);
    float* h0 = (float*)(wsb + OB_H0);
    float* cst= (float*)(wsb + OB_C);
    float* h1 = (float*)(wsb + OB_H1);

    hipMemsetAsync(h0, 0, 4194304, stream);           // h0 + cst
    k_wtrans2<<<1152, 256, 0, stream>>>(cw, whi, wlo);
    k_qkv<<<dim3(16, 128, 4), 256, 0, stream>>>(X, qw, qb, kw, kb, vw, vb,
                                                qmat, kmat, vt);
    k_attn<<<dim3(16, 128), 256, 0, stream>>>(qmat, kmat, vt, axp);

    for (int t = 0; t < 16; ++t) {
        float* hin  = (t & 1) ? h1 : h0;
        float* hout = (t & 1) ? h0 : h1;
        k_cell<<<dim3(8, 4, 8), 256, 0, stream>>>(axp, hin, hout, cst, whi, wlo,
                                                  cb, wci, wcf, wco, out, t);
    }
}